// Round 4
// baseline (565.637 us; speedup 1.0000x reference)
//
#include <hip/hip_runtime.h>
#include <math.h>

// HiPPO-LegS kernel: K[d, l] = C[d]^T A_bar^l B_bar[d], D=1024, N=64, L=4096.
// l = 64q + r decomposition; G_r = A_bar^r, H_q = (A_bar^64)^q via squarings
// S_j = A_bar^(2^j).  All products: mfma_f32_16x16x32_bf16 split-bf16 3-term.
// Round 13: k_expand + k_contract merged into k_main (2048 blocks) with a
// deadlock-free ticket/flag pipeline: each block does one expand tile, then
// {threadfence; done[dch]++; t=ticket++}; t<1024 -> exit, t>=1024 -> claim
// contract tile d=t-1024, spin until done[d>>6]==128, contract. At most 1023
// spinners < 1024 resident slots => guaranteed forward progress with NO
// dispatch-order assumption. Expand blocks reordered dch-major so early dchs
// complete early (contract overlaps the expand tail). Counters in the dead
// WS_SPL region, zeroed by prologue block 0. Math bit-identical to R12.

#define BPAD 72  // bf16 LDS row stride in ushorts (144 B)
#define ARR (64 * BPAD)

// ws layout (float offsets).
#define WS_BBAR   16                      // 1024x64 fp32
#define WS_SPL    65552                   // counters (R13): 32 ints
#define WS_MV     (WS_SPL + 12*8192)      // (unused since R12)
#define WS_GT     (WS_MV + 4096)          // 64 x 4096 (hi 2048 | lo 2048)
#define WS_H      (WS_GT + 64*4096)       // 64 x 4096 (hi | lo)
#define WS_W      (WS_H + 64*4096)        // [d][r][n] fp32
#define WS_X      (WS_W + 1024*4096)      // [d][q][n] fp32

using bf16x8 = __attribute__((ext_vector_type(8))) short;
using f32x4v = __attribute__((ext_vector_type(4))) float;
typedef unsigned short ushort_t;

__device__ __forceinline__ ushort_t f2bf(float x) {
  unsigned u = __builtin_bit_cast(unsigned, x);
  return (ushort_t)((u + 0x7FFFu + ((u >> 16) & 1u)) >> 16);
}
__device__ __forceinline__ float bfhi(float x) {
  unsigned u = __builtin_bit_cast(unsigned, x);
  unsigned r = (u + 0x7FFFu + ((u >> 16) & 1u)) & 0xFFFF0000u;
  return __builtin_bit_cast(float, r);
}
__device__ __forceinline__ ushort_t* usp(float* ws, int foff) {
  return (ushort_t*)(ws + foff);
}
__device__ __forceinline__ const ushort_t* uspc(const float* ws, int foff) {
  return (const ushort_t*)(ws + foff);
}

// ---- 4-wave MFMA 64x64x64 (expand/contract path) ----
__device__ __forceinline__ void mm_frag(const ushort_t* __restrict__ Ah,
                                        const ushort_t* __restrict__ Al,
                                        const ushort_t* __restrict__ Bh,
                                        const ushort_t* __restrict__ Bl,
                                        int w, int lane, f32x4v acc[4]) {
  const int lm = lane & 15, quad = lane >> 4;
  const int ar = (16 * w + lm) * BPAD, ko = quad * 8;
#pragma unroll
  for (int nt = 0; nt < 4; ++nt) { acc[nt][0] = acc[nt][1] = acc[nt][2] = acc[nt][3] = 0.f; }
#pragma unroll
  for (int kc = 0; kc < 64; kc += 32) {
    const bf16x8 ahi = *(const bf16x8*)&Ah[ar + kc + ko];
    const bf16x8 alo = *(const bf16x8*)&Al[ar + kc + ko];
#pragma unroll
    for (int nt = 0; nt < 4; ++nt) {
      const int br = (16 * nt + lm) * BPAD + kc + ko;
      const bf16x8 bhi = *(const bf16x8*)&Bh[br];
      const bf16x8 blo = *(const bf16x8*)&Bl[br];
      acc[nt] = __builtin_amdgcn_mfma_f32_16x16x32_bf16(ahi, bhi, acc[nt], 0, 0, 0);
      acc[nt] = __builtin_amdgcn_mfma_f32_16x16x32_bf16(ahi, blo, acc[nt], 0, 0, 0);
      acc[nt] = __builtin_amdgcn_mfma_f32_16x16x32_bf16(alo, bhi, acc[nt], 0, 0, 0);
    }
  }
}

// ---- 16-wave MFMA 64x64x64: wave (mt,nt) owns one 16x16 tile, 6 MFMA ----
__device__ __forceinline__ void mm_frag16(const ushort_t* __restrict__ Ah,
                                          const ushort_t* __restrict__ Al,
                                          const ushort_t* __restrict__ Bh,
                                          const ushort_t* __restrict__ Bl,
                                          int mt, int nt, int lane, f32x4v& acc) {
  const int lm = lane & 15, quad = lane >> 4;
  const int ar = (16 * mt + lm) * BPAD, br = (16 * nt + lm) * BPAD, ko = quad * 8;
  acc[0] = acc[1] = acc[2] = acc[3] = 0.f;
#pragma unroll
  for (int kc = 0; kc < 64; kc += 32) {
    const bf16x8 ahi = *(const bf16x8*)&Ah[ar + kc + ko];
    const bf16x8 alo = *(const bf16x8*)&Al[ar + kc + ko];
    const bf16x8 bhi = *(const bf16x8*)&Bh[br + kc + ko];
    const bf16x8 blo = *(const bf16x8*)&Bl[br + kc + ko];
    acc = __builtin_amdgcn_mfma_f32_16x16x32_bf16(ahi, bhi, acc, 0, 0, 0);
    acc = __builtin_amdgcn_mfma_f32_16x16x32_bf16(ahi, blo, acc, 0, 0, 0);
    acc = __builtin_amdgcn_mfma_f32_16x16x32_bf16(alo, bhi, acc, 0, 0, 0);
  }
}

// 16-wave D store -> split bf16, BOTH layouts (in-place squaring).
__device__ __forceinline__ void dstore_lds16(const f32x4v& acc,
                                             ushort_t* __restrict__ Ah, ushort_t* __restrict__ Al,
                                             ushort_t* __restrict__ Bth, ushort_t* __restrict__ Btl,
                                             int mt, int nt, int lane) {
  const int lm = lane & 15, quad = lane >> 4;
  const int m0 = 16 * mt + 4 * quad;
  const int n = 16 * nt + lm;
  ushort_t h[4], l[4];
#pragma unroll
  for (int reg = 0; reg < 4; ++reg) {
    const float x = acc[reg];
    h[reg] = f2bf(x); l[reg] = f2bf(x - bfhi(x));
    Ah[(m0 + reg) * BPAD + n] = h[reg];
    Al[(m0 + reg) * BPAD + n] = l[reg];
  }
  uint2 hp, lp;
  hp.x = (unsigned)h[0] | ((unsigned)h[1] << 16);
  hp.y = (unsigned)h[2] | ((unsigned)h[3] << 16);
  lp.x = (unsigned)l[0] | ((unsigned)l[1] << 16);
  lp.y = (unsigned)l[2] | ((unsigned)l[3] << 16);
  *(uint2*)&Bth[n * BPAD + m0] = hp;
  *(uint2*)&Btl[n * BPAD + m0] = lp;
}

// 16-wave D store -> A-layout only (chain intermediates).
__device__ __forceinline__ void dstore_A16(const f32x4v& acc,
                                           ushort_t* __restrict__ Ah, ushort_t* __restrict__ Al,
                                           int mt, int nt, int lane) {
  const int lm = lane & 15, quad = lane >> 4;
  const int m0 = 16 * mt + 4 * quad;
  const int n = 16 * nt + lm;
#pragma unroll
  for (int reg = 0; reg < 4; ++reg) {
    const float x = acc[reg];
    Ah[(m0 + reg) * BPAD + n] = f2bf(x);
    Al[(m0 + reg) * BPAD + n] = f2bf(x - bfhi(x));
  }
}

// packed 64x64 ushort ws region <-> padded LDS (BPAD), NT threads
__device__ __forceinline__ void cp_l2w(const ushort_t* __restrict__ l,
                                       ushort_t* __restrict__ g, int tid, int NT) {
  for (int e = tid; e < 512; e += NT) {
    const int row = e >> 3, c8 = (e & 7) * 8;
    *(uint4*)&g[row * 64 + c8] = *(const uint4*)&l[row * BPAD + c8];
  }
}
__device__ __forceinline__ void cp_w2l(const ushort_t* __restrict__ g,
                                       ushort_t* __restrict__ l, int tid, int NT) {
  for (int e = tid; e < 512; e += NT) {
    const int row = e >> 3, c8 = (e & 7) * 8;
    *(uint4*)&l[row * BPAD + c8] = *(const uint4*)&g[row * 64 + c8];
  }
}

// fp32 global 64x64 -> split bf16 A-layout LDS, NT threads
__device__ __forceinline__ void split_stage(const float* __restrict__ g,
                                            ushort_t* __restrict__ Ah,
                                            ushort_t* __restrict__ Al, int tid, int NT) {
  for (int flat = tid * 4; flat < 4096; flat += NT * 4) {
    const int row = flat >> 6, col = flat & 63;
    const float4 v = *(const float4*)&g[flat];
    ushort_t h0 = f2bf(v.x), h1 = f2bf(v.y), h2 = f2bf(v.z), h3 = f2bf(v.w);
    ushort_t l0 = f2bf(v.x - bfhi(v.x)), l1 = f2bf(v.y - bfhi(v.y));
    ushort_t l2 = f2bf(v.z - bfhi(v.z)), l3 = f2bf(v.w - bfhi(v.w));
    uint2 hp, lp;
    hp.x = (unsigned)h0 | ((unsigned)h1 << 16); hp.y = (unsigned)h2 | ((unsigned)h3 << 16);
    lp.x = (unsigned)l0 | ((unsigned)l1 << 16); lp.y = (unsigned)l2 | ((unsigned)l3 << 16);
    *(uint2*)&Ah[row * BPAD + col] = hp;
    *(uint2*)&Al[row * BPAD + col] = lp;
  }
}

// ---------------------------------------------------------------------------
// K1: k_prologue, 144 blocks x 1024 (16 waves). Unchanged from R12 except
// block 0 zeroes the R13 pipeline counters at WS_SPL.
// ---------------------------------------------------------------------------
__global__ __launch_bounds__(1024) void k_prologue(const float* __restrict__ A,
                                                   const float* __restrict__ Bg,
                                                   const float* __restrict__ logdt,
                                                   float* __restrict__ ws) {
  __shared__ __align__(16) char SM[55296];
  float* Msh  = (float*)SM;                    // 64*65 fp32 (0..16639)
  float* Tm   = (float*)(SM + 16640);          // 64*65 fp32 (..33279)
  float* tmpb = (float*)(SM + 33280);          // 1024 fp32 (..37375, dead post-inv)
  ushort_t* ping = (ushort_t*)SM;              // 4 x ARR (0..36863)
  ushort_t* ca   = (ushort_t*)(SM + 36864);    // 2 x ARR (36864..55295)
  const int p = blockIdx.x, tid = threadIdx.x;
  const int w = tid >> 6, lane = tid & 63;
  const int mt = w >> 2, nt4 = w & 3;
  const int lm = lane & 15, quad = lane >> 4;
  const int NT = 1024;

  const int chain = (p < 128) ? (p >> 6) : 0;
  const int rq = p & 63;

  if (p < 128 && rq == 0) {  // identity export + counter zeroing
    if (p == 0 && tid < 32) ((int*)(ws + WS_SPL))[tid] = 0;
    ushort_t* dstH = usp(ws, (chain ? WS_H : WS_GT));
    ushort_t* dstL = dstH + 4096;
    for (int idx = tid; idx < 4096; idx += NT) {
      const int i = idx >> 6, j = idx & 63;
      dstH[idx] = (i == j) ? (ushort_t)0x3F80 : (ushort_t)0;
      dstL[idx] = 0;
    }
    return;
  }

  // ---- fp32 recursive-doubling inverse of M = I - (dt/2) A (lower-tri) ----
  const float hdt = 0.5f * expf(logdt[0]);
  for (int idx = tid; idx < 4096; idx += NT) {
    const int i = idx >> 6, j = idx & 63;
    Msh[i * 65 + j] = ((i == j) ? 1.f : 0.f) - hdt * A[idx];
    Tm[i * 65 + j] = 0.f;
  }
  __syncthreads();
  if (tid < 64) Tm[tid * 65 + tid] = 1.0f / Msh[tid * 65 + tid];
  __syncthreads();
  for (int lb = 0; lb < 6; ++lb) {
    const int b = 1 << lb;
    const int E = 32 * b;
    for (int e = tid; e < E; e += NT) {
      const int rem = e & (b * b - 1);
      const int pp = e >> (2 * lb);
      const int i = rem >> lb, j = rem & (b - 1);
      const int c0 = pp << (lb + 1), r0 = c0 + b;
      float s = 0.f;
      for (int k = 0; k < b; ++k)
        s += Msh[(r0 + i) * 65 + c0 + k] * Tm[(c0 + k) * 65 + c0 + j];
      tmpb[e] = s;
    }
    __syncthreads();
    for (int e = tid; e < E; e += NT) {
      const int rem = e & (b * b - 1);
      const int pp = e >> (2 * lb);
      const int i = rem >> lb, j = rem & (b - 1);
      const int c0 = pp << (lb + 1), r0 = c0 + b;
      float s = 0.f;
      const float* tp = &tmpb[e - rem];
      for (int k = 0; k < b; ++k)
        s += Tm[(r0 + i) * 65 + r0 + k] * tp[k * b + j];
      Tm[(r0 + i) * 65 + c0 + j] = -s;
    }
    __syncthreads();
  }

  // stash Minv in regs (ping overlays Tm below)
  float mv[4];
#pragma unroll
  for (int t4 = 0; t4 < 4; ++t4) {
    const int idx = tid + NT * t4;
    mv[t4] = Tm[(idx >> 6) * 65 + (idx & 63)];
  }
  __syncthreads();  // all Tm reads done before ping overwrites it

  if (p >= 128) {
    // ---- B_bar chunk: dt * B_chunk @ Minv^T (Bt operand = Minv rows) ----
    const int d0 = (p - 128) * 64;
    const float dtv = expf(logdt[0]);
    ushort_t* Bh = ping;           ushort_t* Bl = ping + ARR;
    ushort_t* Mh = ping + 2 * ARR; ushort_t* Ml = ping + 3 * ARR;
    split_stage(Bg + d0 * 64, Bh, Bl, tid, NT);
#pragma unroll
    for (int t4 = 0; t4 < 4; ++t4) {
      const int idx = tid + NT * t4;
      const int i = idx >> 6, j = idx & 63;
      const float m = mv[t4];
      Mh[i * BPAD + j] = f2bf(m);
      Ml[i * BPAD + j] = f2bf(m - bfhi(m));
    }
    __syncthreads();
    f32x4v acc;
    mm_frag16(Bh, Bl, Mh, Ml, mt, nt4, lane, acc);
    float* od = ws + WS_BBAR + d0 * 64;
#pragma unroll
    for (int reg = 0; reg < 4; ++reg)
      od[(16 * mt + 4 * quad + reg) * 64 + 16 * nt4 + lm] = dtv * acc[reg];
    return;
  }

  // ---- chain blocks: local squaring ladder + interleaved products ----
  const int base6 = chain * 6;
  const int j0   = (__ffs(rq) - 1) + base6;
  const int jmax = (31 - __clz((unsigned)rq)) + base6;
  const bool single = (j0 == jmax);

  // ping = A_bar = 2*Minv - I, in both layouts (split hi/lo)
#pragma unroll
  for (int t4 = 0; t4 < 4; ++t4) {
    const int idx = tid + NT * t4;
    const int i = idx >> 6, j = idx & 63;
    const float v = 2.f * mv[t4] - ((i == j) ? 1.f : 0.f);
    const ushort_t h = f2bf(v), l2 = f2bf(v - bfhi(v));
    ping[0 * ARR + i * BPAD + j] = h; ping[1 * ARR + i * BPAD + j] = l2;
    ping[2 * ARR + j * BPAD + i] = h; ping[3 * ARR + j * BPAD + i] = l2;
  }
  __syncthreads();

  ushort_t* cur = ping;            // S_j, in-place, all 4 arrays
  ushort_t* cah = ca;              // accumulated product, A-layout hi
  ushort_t* cal = ca + ARR;        //                       A-layout lo

  for (int j = 0; j <= jmax; ++j) {
    // invariant: cur holds S_j complete (barrier'd)
    const bool isprod = (j > j0) && ((rq >> (j - base6)) & 1);
    const bool dosq = (j < jmax);
    if (j == j0 && !single) {
      // ca = S_j0 (A-layout hi/lo copy)
      const int arr = tid >> 9, ei = tid & 511;
      const int row = ei >> 3, c8 = (ei & 7) * 8;
      *(uint4*)&ca[arr * ARR + row * BPAD + c8] =
          *(const uint4*)&cur[arr * ARR + row * BPAD + c8];
    }
    f32x4v accp, accs;
    if (isprod) mm_frag16(cah, cal, cur + 2 * ARR, cur + 3 * ARR, mt, nt4, lane, accp);
    if (dosq)   mm_frag16(cur, cur + ARR, cur + 2 * ARR, cur + 3 * ARR, mt, nt4, lane, accs);
    __syncthreads();  // all reads (and the j0-copy writes) done
    if (isprod && !dosq) {
      // final product: export straight from registers
      const int m0 = 16 * mt + 4 * quad, n = 16 * nt4 + lm;
      ushort_t h[4], l[4];
#pragma unroll
      for (int reg = 0; reg < 4; ++reg) {
        const float x = accp[reg];
        h[reg] = f2bf(x); l[reg] = f2bf(x - bfhi(x));
      }
      if (chain == 0) {  // Gt = (product)^T : row n, cols m0..m0+3, packed
        ushort_t* dstH = usp(ws, WS_GT + rq * 4096);
        ushort_t* dstL = dstH + 4096;
        uint2 hp, lp;
        hp.x = (unsigned)h[0] | ((unsigned)h[1] << 16);
        hp.y = (unsigned)h[2] | ((unsigned)h[3] << 16);
        lp.x = (unsigned)l[0] | ((unsigned)l[1] << 16);
        lp.y = (unsigned)l[2] | ((unsigned)l[3] << 16);
        *(uint2*)&dstH[n * 64 + m0] = hp;
        *(uint2*)&dstL[n * 64 + m0] = lp;
      } else {           // H row-major: rows m0..m0+3, col n, scalar
        ushort_t* dstH = usp(ws, WS_H + rq * 4096);
        ushort_t* dstL = dstH + 4096;
#pragma unroll
        for (int reg = 0; reg < 4; ++reg) {
          dstH[(m0 + reg) * 64 + n] = h[reg];
          dstL[(m0 + reg) * 64 + n] = l[reg];
        }
      }
      return;
    }
    if (isprod) dstore_A16(accp, cah, cal, mt, nt4, lane);
    if (dosq)   dstore_lds16(accs, cur, cur + ARR, cur + 2 * ARR, cur + 3 * ARR,
                             mt, nt4, lane);
    __syncthreads();
  }

  // single-bit chains: export S_{j0} (chain0 transposed = Bt arrays)
  if (chain == 0) {
    ushort_t* dstH = usp(ws, WS_GT + rq * 4096);
    ushort_t* dstL = dstH + 4096;
    cp_l2w(cur + 2 * ARR, dstH, tid, NT);
    cp_l2w(cur + 3 * ARR, dstL, tid, NT);
  } else {
    ushort_t* dstH = usp(ws, WS_H + rq * 4096);
    ushort_t* dstL = dstH + 4096;
    cp_l2w(cur, dstH, tid, NT);
    cp_l2w(cur + ARR, dstL, tid, NT);
  }
}

// ---------------------------------------------------------------------------
// K2: k_main, 2048 blocks x 256. Expand tile + ticketed contract.
//  expand p = dch*128 + chain*64 + rr  (dch-major: early dchs finish first)
//  after expand: done[dch]++, t=ticket++; t<1024 exit; else contract d=t-1024
//  (spin until done[d>>6]==128). <=1023 spinners < 1024 slots => no deadlock.
// ---------------------------------------------------------------------------
__global__ __launch_bounds__(256) void k_main(const float* __restrict__ Cg,
                                              const float* __restrict__ Dg,
                                              float* __restrict__ ws,
                                              float* __restrict__ out) {
  __shared__ __align__(16) ushort_t SMe[4 * ARR];
  __shared__ int tkt;
  const int p = blockIdx.x, tid = threadIdx.x;
  const int w = tid >> 6, lane = tid & 63;
  const int lm = lane & 15, quad = lane >> 4;

  int* ctr = (int*)(ws + WS_SPL);  // [0..15] done per dch, [16] ticket

  // ---------------- expand tile ----------------
  {
    const int dch = p >> 7, chain = (p >> 6) & 1, rr = p & 63;
    const int d0 = dch * 64;
    ushort_t* Asp = SMe;            // hi, lo
    ushort_t* Bsp = SMe + 2 * ARR;  // hi, lo

    split_stage(chain ? (ws + WS_BBAR + d0 * 64) : (Cg + d0 * 64),
                Asp, Asp + ARR, tid, 256);
    const int mb = (chain ? WS_H : WS_GT) + rr * 4096;
    cp_w2l(uspc(ws, mb + 0), Bsp, tid, 256);
    cp_w2l(uspc(ws, mb + 2048), Bsp + ARR, tid, 256);
    __syncthreads();

    f32x4v acc[4];
    mm_frag(Asp, Asp + ARR, Bsp, Bsp + ARR, w, lane, acc);

    float* dst = ws + (chain ? WS_X : WS_W) + d0 * 4096 + rr * 64;
#pragma unroll
    for (int nt = 0; nt < 4; ++nt)
#pragma unroll
      for (int reg = 0; reg < 4; ++reg)
        dst[(16 * w + 4 * quad + reg) * 4096 + 16 * nt + lm] = acc[nt][reg];

    // publish: release fence by every thread, then barrier, then counters
    __threadfence();
    __syncthreads();
    if (tid == 0) {
      __hip_atomic_fetch_add(&ctr[dch], 1, __ATOMIC_RELEASE, __HIP_MEMORY_SCOPE_AGENT);
      tkt = __hip_atomic_fetch_add(&ctr[16], 1, __ATOMIC_ACQ_REL, __HIP_MEMORY_SCOPE_AGENT);
    }
    __syncthreads();
  }

  const int t = tkt;
  if (t < 1024) return;   // early finishers free their slots
  const int d = t - 1024; // claimed contract tile

  if (tid == 0) {
    while (__hip_atomic_load(&ctr[d >> 6], __ATOMIC_ACQUIRE, __HIP_MEMORY_SCOPE_AGENT) < 128)
      __builtin_amdgcn_s_sleep(4);
  }
  __syncthreads();
  __threadfence();  // acquire: make producers' W/X stores visible to all lanes

  // ---------------- contract tile d ----------------
  ushort_t* XhiL = SMe;
  ushort_t* XloL = SMe + ARR;
  ushort_t* WhiL = SMe + 2 * ARR;
  ushort_t* WloL = SMe + 3 * ARR;
  const float* Wg = ws + WS_W + d * 4096;
  const float* Xg = ws + WS_X + d * 4096;

#pragma unroll
  for (int j = 0; j < 4; ++j) {
    const int flat = j * 1024 + tid * 4;
    const int row = flat >> 6, col = flat & 63;
    const float4 wv = *(const float4*)&Wg[flat];
    const float4 xv = *(const float4*)&Xg[flat];
    const int o = row * BPAD + col;
#pragma unroll
    for (int s = 0; s < 2; ++s) {
      const float4 v = s ? xv : wv;
      ushort_t h0 = f2bf(v.x), h1 = f2bf(v.y), h2 = f2bf(v.z), h3 = f2bf(v.w);
      ushort_t l0 = f2bf(v.x - bfhi(v.x)), l1 = f2bf(v.y - bfhi(v.y));
      ushort_t l2 = f2bf(v.z - bfhi(v.z)), l3 = f2bf(v.w - bfhi(v.w));
      uint2 hp, lp;
      hp.x = (unsigned)h0 | ((unsigned)h1 << 16); hp.y = (unsigned)h2 | ((unsigned)h3 << 16);
      lp.x = (unsigned)l0 | ((unsigned)l1 << 16); lp.y = (unsigned)l2 | ((unsigned)l3 << 16);
      *(uint2*)&(s ? XhiL : WhiL)[o] = hp;
      *(uint2*)&(s ? XloL : WloL)[o] = lp;
    }
  }
  __syncthreads();

  const int qrow = 16 * w + lm;
  const int koff = quad * 8;

  f32x4v acc[4];
#pragma unroll
  for (int nt = 0; nt < 4; ++nt) { acc[nt][0] = 0.f; acc[nt][1] = 0.f; acc[nt][2] = 0.f; acc[nt][3] = 0.f; }

#pragma unroll
  for (int kc = 0; kc < 64; kc += 32) {
    const bf16x8 ahi = *(const bf16x8*)&XhiL[qrow * BPAD + kc + koff];
    const bf16x8 alo = *(const bf16x8*)&XloL[qrow * BPAD + kc + koff];
#pragma unroll
    for (int nt = 0; nt < 4; ++nt) {
      const int rrow = 16 * nt + lm;
      const bf16x8 bhi = *(const bf16x8*)&WhiL[rrow * BPAD + kc + koff];
      const bf16x8 blo = *(const bf16x8*)&WloL[rrow * BPAD + kc + koff];
      acc[nt] = __builtin_amdgcn_mfma_f32_16x16x32_bf16(ahi, bhi, acc[nt], 0, 0, 0);
      acc[nt] = __builtin_amdgcn_mfma_f32_16x16x32_bf16(ahi, blo, acc[nt], 0, 0, 0);
      acc[nt] = __builtin_amdgcn_mfma_f32_16x16x32_bf16(alo, bhi, acc[nt], 0, 0, 0);
    }
  }

  if (tid == 0) acc[0][0] += Dg[d];

  float* od = out + d * 4096;
#pragma unroll
  for (int nt = 0; nt < 4; ++nt) {
#pragma unroll
    for (int reg = 0; reg < 4; ++reg) {
      const int q = 16 * w + quad * 4 + reg;
      od[q * 64 + 16 * nt + lm] = acc[nt][reg];
    }
  }
}

extern "C" void kernel_launch(void* const* d_in, const int* in_sizes, int n_in,
                              void* d_out, int out_size, void* d_ws, size_t ws_size,
                              hipStream_t stream) {
  const float* A     = (const float*)d_in[0];  // A_ct 64x64
  const float* B     = (const float*)d_in[1];  // 1024x64
  const float* C     = (const float*)d_in[2];  // 1024x64
  const float* Dv    = (const float*)d_in[3];  // 1024
  const float* logdt = (const float*)d_in[4];  // scalar
  float* ws  = (float*)d_ws;
  float* out = (float*)d_out;                  // 1024*4096 fp32

  hipLaunchKernelGGL(k_prologue, dim3(144),  dim3(1024), 0, stream, A, B, logdt, ws);
  hipLaunchKernelGGL(k_main,     dim3(2048), dim3(256),  0, stream, C, Dv, ws, out);
}

// Round 5
// 118.528 us; speedup vs baseline: 4.7722x; 4.7722x over previous
//
#include <hip/hip_runtime.h>
#include <math.h>

// HiPPO-LegS kernel: K[d, l] = C[d]^T A_bar^l B_bar[d], D=1024, N=64, L=4096.
// l = 64q + r decomposition; G_r = A_bar^r, H_q = (A_bar^64)^q via squarings
// S_j = A_bar^(2^j).  All products: mfma_f32_16x16x32_bf16 split-bf16 3-term.
// Round 14: R13's atomic-pipeline REVERTED (470us k_main, 97% idle — lesson:
// cross-block spin/grid.sync both cost O(100us) on this stack; launch gaps
// ~2us are the cheap sync). Back to R12's proven 3-kernel structure. Only
// change vs R12: k_contract block->d mapping is XCD-swizzled so that
// (d>>6) % 8 == blockIdx % 8, matching k_expand's producer placement
// (p mod 8 = dch mod 8) => W/X reads hit the producer XCD's L2 (4 MB/XCD).
// Math bit-identical (absmax must stay 0.0002441406).

#define BPAD 72  // bf16 LDS row stride in ushorts (144 B)
#define ARR (64 * BPAD)

// ws layout (float offsets).
#define WS_BBAR   16                      // 1024x64 fp32
#define WS_SPL    65552                   // (unused)
#define WS_MV     (WS_SPL + 12*8192)      // (unused)
#define WS_GT     (WS_MV + 4096)          // 64 x 4096 (hi 2048 | lo 2048)
#define WS_H      (WS_GT + 64*4096)       // 64 x 4096 (hi | lo)
#define WS_W      (WS_H + 64*4096)        // [d][r][n] fp32
#define WS_X      (WS_W + 1024*4096)      // [d][q][n] fp32

using bf16x8 = __attribute__((ext_vector_type(8))) short;
using f32x4v = __attribute__((ext_vector_type(4))) float;
typedef unsigned short ushort_t;

__device__ __forceinline__ ushort_t f2bf(float x) {
  unsigned u = __builtin_bit_cast(unsigned, x);
  return (ushort_t)((u + 0x7FFFu + ((u >> 16) & 1u)) >> 16);
}
__device__ __forceinline__ float bfhi(float x) {
  unsigned u = __builtin_bit_cast(unsigned, x);
  unsigned r = (u + 0x7FFFu + ((u >> 16) & 1u)) & 0xFFFF0000u;
  return __builtin_bit_cast(float, r);
}
__device__ __forceinline__ ushort_t* usp(float* ws, int foff) {
  return (ushort_t*)(ws + foff);
}
__device__ __forceinline__ const ushort_t* uspc(const float* ws, int foff) {
  return (const ushort_t*)(ws + foff);
}

// ---- 4-wave MFMA 64x64x64 (expand path) ----
__device__ __forceinline__ void mm_frag(const ushort_t* __restrict__ Ah,
                                        const ushort_t* __restrict__ Al,
                                        const ushort_t* __restrict__ Bh,
                                        const ushort_t* __restrict__ Bl,
                                        int w, int lane, f32x4v acc[4]) {
  const int lm = lane & 15, quad = lane >> 4;
  const int ar = (16 * w + lm) * BPAD, ko = quad * 8;
#pragma unroll
  for (int nt = 0; nt < 4; ++nt) { acc[nt][0] = acc[nt][1] = acc[nt][2] = acc[nt][3] = 0.f; }
#pragma unroll
  for (int kc = 0; kc < 64; kc += 32) {
    const bf16x8 ahi = *(const bf16x8*)&Ah[ar + kc + ko];
    const bf16x8 alo = *(const bf16x8*)&Al[ar + kc + ko];
#pragma unroll
    for (int nt = 0; nt < 4; ++nt) {
      const int br = (16 * nt + lm) * BPAD + kc + ko;
      const bf16x8 bhi = *(const bf16x8*)&Bh[br];
      const bf16x8 blo = *(const bf16x8*)&Bl[br];
      acc[nt] = __builtin_amdgcn_mfma_f32_16x16x32_bf16(ahi, bhi, acc[nt], 0, 0, 0);
      acc[nt] = __builtin_amdgcn_mfma_f32_16x16x32_bf16(ahi, blo, acc[nt], 0, 0, 0);
      acc[nt] = __builtin_amdgcn_mfma_f32_16x16x32_bf16(alo, bhi, acc[nt], 0, 0, 0);
    }
  }
}

// ---- 16-wave MFMA 64x64x64: wave (mt,nt) owns one 16x16 tile, 6 MFMA ----
__device__ __forceinline__ void mm_frag16(const ushort_t* __restrict__ Ah,
                                          const ushort_t* __restrict__ Al,
                                          const ushort_t* __restrict__ Bh,
                                          const ushort_t* __restrict__ Bl,
                                          int mt, int nt, int lane, f32x4v& acc) {
  const int lm = lane & 15, quad = lane >> 4;
  const int ar = (16 * mt + lm) * BPAD, br = (16 * nt + lm) * BPAD, ko = quad * 8;
  acc[0] = acc[1] = acc[2] = acc[3] = 0.f;
#pragma unroll
  for (int kc = 0; kc < 64; kc += 32) {
    const bf16x8 ahi = *(const bf16x8*)&Ah[ar + kc + ko];
    const bf16x8 alo = *(const bf16x8*)&Al[ar + kc + ko];
    const bf16x8 bhi = *(const bf16x8*)&Bh[br + kc + ko];
    const bf16x8 blo = *(const bf16x8*)&Bl[br + kc + ko];
    acc = __builtin_amdgcn_mfma_f32_16x16x32_bf16(ahi, bhi, acc, 0, 0, 0);
    acc = __builtin_amdgcn_mfma_f32_16x16x32_bf16(ahi, blo, acc, 0, 0, 0);
    acc = __builtin_amdgcn_mfma_f32_16x16x32_bf16(alo, bhi, acc, 0, 0, 0);
  }
}

// 16-wave D store -> split bf16, BOTH layouts (in-place squaring).
__device__ __forceinline__ void dstore_lds16(const f32x4v& acc,
                                             ushort_t* __restrict__ Ah, ushort_t* __restrict__ Al,
                                             ushort_t* __restrict__ Bth, ushort_t* __restrict__ Btl,
                                             int mt, int nt, int lane) {
  const int lm = lane & 15, quad = lane >> 4;
  const int m0 = 16 * mt + 4 * quad;
  const int n = 16 * nt + lm;
  ushort_t h[4], l[4];
#pragma unroll
  for (int reg = 0; reg < 4; ++reg) {
    const float x = acc[reg];
    h[reg] = f2bf(x); l[reg] = f2bf(x - bfhi(x));
    Ah[(m0 + reg) * BPAD + n] = h[reg];
    Al[(m0 + reg) * BPAD + n] = l[reg];
  }
  uint2 hp, lp;
  hp.x = (unsigned)h[0] | ((unsigned)h[1] << 16);
  hp.y = (unsigned)h[2] | ((unsigned)h[3] << 16);
  lp.x = (unsigned)l[0] | ((unsigned)l[1] << 16);
  lp.y = (unsigned)l[2] | ((unsigned)l[3] << 16);
  *(uint2*)&Bth[n * BPAD + m0] = hp;
  *(uint2*)&Btl[n * BPAD + m0] = lp;
}

// 16-wave D store -> A-layout only (chain intermediates).
__device__ __forceinline__ void dstore_A16(const f32x4v& acc,
                                           ushort_t* __restrict__ Ah, ushort_t* __restrict__ Al,
                                           int mt, int nt, int lane) {
  const int lm = lane & 15, quad = lane >> 4;
  const int m0 = 16 * mt + 4 * quad;
  const int n = 16 * nt + lm;
#pragma unroll
  for (int reg = 0; reg < 4; ++reg) {
    const float x = acc[reg];
    Ah[(m0 + reg) * BPAD + n] = f2bf(x);
    Al[(m0 + reg) * BPAD + n] = f2bf(x - bfhi(x));
  }
}

// packed 64x64 ushort ws region <-> padded LDS (BPAD), NT threads
__device__ __forceinline__ void cp_l2w(const ushort_t* __restrict__ l,
                                       ushort_t* __restrict__ g, int tid, int NT) {
  for (int e = tid; e < 512; e += NT) {
    const int row = e >> 3, c8 = (e & 7) * 8;
    *(uint4*)&g[row * 64 + c8] = *(const uint4*)&l[row * BPAD + c8];
  }
}
__device__ __forceinline__ void cp_w2l(const ushort_t* __restrict__ g,
                                       ushort_t* __restrict__ l, int tid, int NT) {
  for (int e = tid; e < 512; e += NT) {
    const int row = e >> 3, c8 = (e & 7) * 8;
    *(uint4*)&l[row * BPAD + c8] = *(const uint4*)&g[row * 64 + c8];
  }
}

// fp32 global 64x64 -> split bf16 A-layout LDS, NT threads
__device__ __forceinline__ void split_stage(const float* __restrict__ g,
                                            ushort_t* __restrict__ Ah,
                                            ushort_t* __restrict__ Al, int tid, int NT) {
  for (int flat = tid * 4; flat < 4096; flat += NT * 4) {
    const int row = flat >> 6, col = flat & 63;
    const float4 v = *(const float4*)&g[flat];
    ushort_t h0 = f2bf(v.x), h1 = f2bf(v.y), h2 = f2bf(v.z), h3 = f2bf(v.w);
    ushort_t l0 = f2bf(v.x - bfhi(v.x)), l1 = f2bf(v.y - bfhi(v.y));
    ushort_t l2 = f2bf(v.z - bfhi(v.z)), l3 = f2bf(v.w - bfhi(v.w));
    uint2 hp, lp;
    hp.x = (unsigned)h0 | ((unsigned)h1 << 16); hp.y = (unsigned)h2 | ((unsigned)h3 << 16);
    lp.x = (unsigned)l0 | ((unsigned)l1 << 16); lp.y = (unsigned)l2 | ((unsigned)l3 << 16);
    *(uint2*)&Ah[row * BPAD + col] = hp;
    *(uint2*)&Al[row * BPAD + col] = lp;
  }
}

// ---------------------------------------------------------------------------
// K1: k_prologue, 144 blocks x 1024 (16 waves). Unchanged from R12.
// ---------------------------------------------------------------------------
__global__ __launch_bounds__(1024) void k_prologue(const float* __restrict__ A,
                                                   const float* __restrict__ Bg,
                                                   const float* __restrict__ logdt,
                                                   float* __restrict__ ws) {
  __shared__ __align__(16) char SM[55296];
  float* Msh  = (float*)SM;                    // 64*65 fp32 (0..16639)
  float* Tm   = (float*)(SM + 16640);          // 64*65 fp32 (..33279)
  float* tmpb = (float*)(SM + 33280);          // 1024 fp32 (..37375, dead post-inv)
  ushort_t* ping = (ushort_t*)SM;              // 4 x ARR (0..36863)
  ushort_t* ca   = (ushort_t*)(SM + 36864);    // 2 x ARR (36864..55295)
  const int p = blockIdx.x, tid = threadIdx.x;
  const int w = tid >> 6, lane = tid & 63;
  const int mt = w >> 2, nt4 = w & 3;
  const int lm = lane & 15, quad = lane >> 4;
  const int NT = 1024;

  const int chain = (p < 128) ? (p >> 6) : 0;
  const int rq = p & 63;

  if (p < 128 && rq == 0) {  // identity export, no inverse needed
    ushort_t* dstH = usp(ws, (chain ? WS_H : WS_GT));
    ushort_t* dstL = dstH + 4096;
    for (int idx = tid; idx < 4096; idx += NT) {
      const int i = idx >> 6, j = idx & 63;
      dstH[idx] = (i == j) ? (ushort_t)0x3F80 : (ushort_t)0;
      dstL[idx] = 0;
    }
    return;
  }

  // ---- fp32 recursive-doubling inverse of M = I - (dt/2) A (lower-tri) ----
  const float hdt = 0.5f * expf(logdt[0]);
  for (int idx = tid; idx < 4096; idx += NT) {
    const int i = idx >> 6, j = idx & 63;
    Msh[i * 65 + j] = ((i == j) ? 1.f : 0.f) - hdt * A[idx];
    Tm[i * 65 + j] = 0.f;
  }
  __syncthreads();
  if (tid < 64) Tm[tid * 65 + tid] = 1.0f / Msh[tid * 65 + tid];
  __syncthreads();
  for (int lb = 0; lb < 6; ++lb) {
    const int b = 1 << lb;
    const int E = 32 * b;
    for (int e = tid; e < E; e += NT) {
      const int rem = e & (b * b - 1);
      const int pp = e >> (2 * lb);
      const int i = rem >> lb, j = rem & (b - 1);
      const int c0 = pp << (lb + 1), r0 = c0 + b;
      float s = 0.f;
      for (int k = 0; k < b; ++k)
        s += Msh[(r0 + i) * 65 + c0 + k] * Tm[(c0 + k) * 65 + c0 + j];
      tmpb[e] = s;
    }
    __syncthreads();
    for (int e = tid; e < E; e += NT) {
      const int rem = e & (b * b - 1);
      const int pp = e >> (2 * lb);
      const int i = rem >> lb, j = rem & (b - 1);
      const int c0 = pp << (lb + 1), r0 = c0 + b;
      float s = 0.f;
      const float* tp = &tmpb[e - rem];
      for (int k = 0; k < b; ++k)
        s += Tm[(r0 + i) * 65 + r0 + k] * tp[k * b + j];
      Tm[(r0 + i) * 65 + c0 + j] = -s;
    }
    __syncthreads();
  }

  // stash Minv in regs (ping overlays Tm below)
  float mv[4];
#pragma unroll
  for (int t4 = 0; t4 < 4; ++t4) {
    const int idx = tid + NT * t4;
    mv[t4] = Tm[(idx >> 6) * 65 + (idx & 63)];
  }
  __syncthreads();  // all Tm reads done before ping overwrites it

  if (p >= 128) {
    // ---- B_bar chunk: dt * B_chunk @ Minv^T (Bt operand = Minv rows) ----
    const int d0 = (p - 128) * 64;
    const float dtv = expf(logdt[0]);
    ushort_t* Bh = ping;           ushort_t* Bl = ping + ARR;
    ushort_t* Mh = ping + 2 * ARR; ushort_t* Ml = ping + 3 * ARR;
    split_stage(Bg + d0 * 64, Bh, Bl, tid, NT);
#pragma unroll
    for (int t4 = 0; t4 < 4; ++t4) {
      const int idx = tid + NT * t4;
      const int i = idx >> 6, j = idx & 63;
      const float m = mv[t4];
      Mh[i * BPAD + j] = f2bf(m);
      Ml[i * BPAD + j] = f2bf(m - bfhi(m));
    }
    __syncthreads();
    f32x4v acc;
    mm_frag16(Bh, Bl, Mh, Ml, mt, nt4, lane, acc);
    float* od = ws + WS_BBAR + d0 * 64;
#pragma unroll
    for (int reg = 0; reg < 4; ++reg)
      od[(16 * mt + 4 * quad + reg) * 64 + 16 * nt4 + lm] = dtv * acc[reg];
    return;
  }

  // ---- chain blocks: local squaring ladder + interleaved products ----
  const int base6 = chain * 6;
  const int j0   = (__ffs(rq) - 1) + base6;
  const int jmax = (31 - __clz((unsigned)rq)) + base6;
  const bool single = (j0 == jmax);

  // ping = A_bar = 2*Minv - I, in both layouts (split hi/lo)
#pragma unroll
  for (int t4 = 0; t4 < 4; ++t4) {
    const int idx = tid + NT * t4;
    const int i = idx >> 6, j = idx & 63;
    const float v = 2.f * mv[t4] - ((i == j) ? 1.f : 0.f);
    const ushort_t h = f2bf(v), l2 = f2bf(v - bfhi(v));
    ping[0 * ARR + i * BPAD + j] = h; ping[1 * ARR + i * BPAD + j] = l2;
    ping[2 * ARR + j * BPAD + i] = h; ping[3 * ARR + j * BPAD + i] = l2;
  }
  __syncthreads();

  ushort_t* cur = ping;            // S_j, in-place, all 4 arrays
  ushort_t* cah = ca;              // accumulated product, A-layout hi
  ushort_t* cal = ca + ARR;        //                       A-layout lo

  for (int j = 0; j <= jmax; ++j) {
    // invariant: cur holds S_j complete (barrier'd)
    const bool isprod = (j > j0) && ((rq >> (j - base6)) & 1);
    const bool dosq = (j < jmax);
    if (j == j0 && !single) {
      // ca = S_j0 (A-layout hi/lo copy)
      const int arr = tid >> 9, ei = tid & 511;
      const int row = ei >> 3, c8 = (ei & 7) * 8;
      *(uint4*)&ca[arr * ARR + row * BPAD + c8] =
          *(const uint4*)&cur[arr * ARR + row * BPAD + c8];
    }
    f32x4v accp, accs;
    if (isprod) mm_frag16(cah, cal, cur + 2 * ARR, cur + 3 * ARR, mt, nt4, lane, accp);
    if (dosq)   mm_frag16(cur, cur + ARR, cur + 2 * ARR, cur + 3 * ARR, mt, nt4, lane, accs);
    __syncthreads();  // all reads (and the j0-copy writes) done
    if (isprod && !dosq) {
      // final product: export straight from registers
      const int m0 = 16 * mt + 4 * quad, n = 16 * nt4 + lm;
      ushort_t h[4], l[4];
#pragma unroll
      for (int reg = 0; reg < 4; ++reg) {
        const float x = accp[reg];
        h[reg] = f2bf(x); l[reg] = f2bf(x - bfhi(x));
      }
      if (chain == 0) {  // Gt = (product)^T : row n, cols m0..m0+3, packed
        ushort_t* dstH = usp(ws, WS_GT + rq * 4096);
        ushort_t* dstL = dstH + 4096;
        uint2 hp, lp;
        hp.x = (unsigned)h[0] | ((unsigned)h[1] << 16);
        hp.y = (unsigned)h[2] | ((unsigned)h[3] << 16);
        lp.x = (unsigned)l[0] | ((unsigned)l[1] << 16);
        lp.y = (unsigned)l[2] | ((unsigned)l[3] << 16);
        *(uint2*)&dstH[n * 64 + m0] = hp;
        *(uint2*)&dstL[n * 64 + m0] = lp;
      } else {           // H row-major: rows m0..m0+3, col n, scalar
        ushort_t* dstH = usp(ws, WS_H + rq * 4096);
        ushort_t* dstL = dstH + 4096;
#pragma unroll
        for (int reg = 0; reg < 4; ++reg) {
          dstH[(m0 + reg) * 64 + n] = h[reg];
          dstL[(m0 + reg) * 64 + n] = l[reg];
        }
      }
      return;
    }
    if (isprod) dstore_A16(accp, cah, cal, mt, nt4, lane);
    if (dosq)   dstore_lds16(accs, cur, cur + ARR, cur + 2 * ARR, cur + 3 * ARR,
                             mt, nt4, lane);
    __syncthreads();
  }

  // single-bit chains: export S_{j0} (chain0 transposed = Bt arrays)
  if (chain == 0) {
    ushort_t* dstH = usp(ws, WS_GT + rq * 4096);
    ushort_t* dstL = dstH + 4096;
    cp_l2w(cur + 2 * ARR, dstH, tid, NT);
    cp_l2w(cur + 3 * ARR, dstL, tid, NT);
  } else {
    ushort_t* dstH = usp(ws, WS_H + rq * 4096);
    ushort_t* dstL = dstH + 4096;
    cp_l2w(cur, dstH, tid, NT);
    cp_l2w(cur + ARR, dstL, tid, NT);
  }
}

// ---------------------------------------------------------------------------
// K2: 2048 blocks x 256. Block = (chain, rr, dch); p mod 8 == dch mod 8, so
// all producers of a dch share an XCD (consumed by k_contract's swizzle).
// ---------------------------------------------------------------------------
__global__ __launch_bounds__(256) void k_expand(const float* __restrict__ Cg,
                                                float* __restrict__ ws) {
  __shared__ __align__(16) ushort_t SMe[4 * ARR];
  ushort_t* Asp = SMe;            // hi, lo
  ushort_t* Bsp = SMe + 2 * ARR;  // hi, lo
  const int p = blockIdx.x, tid = threadIdx.x;
  const int chain = p >> 10, rr = (p >> 4) & 63, dch = p & 15;
  const int w = tid >> 6, lane = tid & 63;
  const int d0 = dch * 64;

  split_stage(chain ? (ws + WS_BBAR + d0 * 64) : (Cg + d0 * 64), Asp, Asp + ARR, tid, 256);
  const int mb = (chain ? WS_H : WS_GT) + rr * 4096;
  cp_w2l(uspc(ws, mb + 0), Bsp, tid, 256);
  cp_w2l(uspc(ws, mb + 2048), Bsp + ARR, tid, 256);
  __syncthreads();

  f32x4v acc[4];
  mm_frag(Asp, Asp + ARR, Bsp, Bsp + ARR, w, lane, acc);

  const int lm = lane & 15, quad = lane >> 4;
  float* dst = ws + (chain ? WS_X : WS_W) + d0 * 4096 + rr * 64;
#pragma unroll
  for (int nt = 0; nt < 4; ++nt)
#pragma unroll
    for (int reg = 0; reg < 4; ++reg)
      dst[(16 * w + 4 * quad + reg) * 4096 + 16 * nt + lm] = acc[nt][reg];
}

// ---------------------------------------------------------------------------
// K3: 1024 blocks x 256 — XCD-swizzled d mapping: (d>>6)%8 == blockIdx%8 so
// W/X reads hit the producer XCD's L2. Otherwise unchanged.
// ---------------------------------------------------------------------------
__global__ __launch_bounds__(256) void k_contract(const float* __restrict__ Dg,
                                                  const float* __restrict__ ws,
                                                  float* __restrict__ out) {
  __shared__ __align__(16) ushort_t XhiL[64 * BPAD];
  __shared__ __align__(16) ushort_t XloL[64 * BPAD];
  __shared__ __align__(16) ushort_t WhiL[64 * BPAD];
  __shared__ __align__(16) ushort_t WloL[64 * BPAD];
  const int b = blockIdx.x, tid = threadIdx.x;
  // d such that (d>>6) % 8 == b % 8  (bijective over 0..1023)
  const int x = b & 7, k = b >> 3;
  const int d = ((x + ((k >> 6) << 3)) << 6) | (k & 63);
  const float* Wg = ws + WS_W + d * 4096;
  const float* Xg = ws + WS_X + d * 4096;

#pragma unroll
  for (int j = 0; j < 4; ++j) {
    const int flat = j * 1024 + tid * 4;
    const int row = flat >> 6, col = flat & 63;
    const float4 wv = *(const float4*)&Wg[flat];
    const float4 xv = *(const float4*)&Xg[flat];
    const int o = row * BPAD + col;
#pragma unroll
    for (int s = 0; s < 2; ++s) {
      const float4 v = s ? xv : wv;
      ushort_t h0 = f2bf(v.x), h1 = f2bf(v.y), h2 = f2bf(v.z), h3 = f2bf(v.w);
      ushort_t l0 = f2bf(v.x - bfhi(v.x)), l1 = f2bf(v.y - bfhi(v.y));
      ushort_t l2 = f2bf(v.z - bfhi(v.z)), l3 = f2bf(v.w - bfhi(v.w));
      uint2 hp, lp;
      hp.x = (unsigned)h0 | ((unsigned)h1 << 16); hp.y = (unsigned)h2 | ((unsigned)h3 << 16);
      lp.x = (unsigned)l0 | ((unsigned)l1 << 16); lp.y = (unsigned)l2 | ((unsigned)l3 << 16);
      *(uint2*)&(s ? XhiL : WhiL)[o] = hp;
      *(uint2*)&(s ? XloL : WloL)[o] = lp;
    }
  }
  __syncthreads();

  const int w = tid >> 6, lane = tid & 63;
  const int lm = lane & 15, quad = lane >> 4;
  const int qrow = 16 * w + lm;
  const int koff = quad * 8;

  f32x4v acc[4];
#pragma unroll
  for (int nt = 0; nt < 4; ++nt) { acc[nt][0] = 0.f; acc[nt][1] = 0.f; acc[nt][2] = 0.f; acc[nt][3] = 0.f; }

#pragma unroll
  for (int kc = 0; kc < 64; kc += 32) {
    const bf16x8 ahi = *(const bf16x8*)&XhiL[qrow * BPAD + kc + koff];
    const bf16x8 alo = *(const bf16x8*)&XloL[qrow * BPAD + kc + koff];
#pragma unroll
    for (int nt = 0; nt < 4; ++nt) {
      const int rrow = 16 * nt + lm;
      const bf16x8 bhi = *(const bf16x8*)&WhiL[rrow * BPAD + kc + koff];
      const bf16x8 blo = *(const bf16x8*)&WloL[rrow * BPAD + kc + koff];
      acc[nt] = __builtin_amdgcn_mfma_f32_16x16x32_bf16(ahi, bhi, acc[nt], 0, 0, 0);
      acc[nt] = __builtin_amdgcn_mfma_f32_16x16x32_bf16(ahi, blo, acc[nt], 0, 0, 0);
      acc[nt] = __builtin_amdgcn_mfma_f32_16x16x32_bf16(alo, bhi, acc[nt], 0, 0, 0);
    }
  }

  if (tid == 0) acc[0][0] += Dg[d];

  float* od = out + d * 4096;
#pragma unroll
  for (int nt = 0; nt < 4; ++nt) {
#pragma unroll
    for (int reg = 0; reg < 4; ++reg) {
      const int q = 16 * w + quad * 4 + reg;
      od[q * 64 + 16 * nt + lm] = acc[nt][reg];
    }
  }
}

extern "C" void kernel_launch(void* const* d_in, const int* in_sizes, int n_in,
                              void* d_out, int out_size, void* d_ws, size_t ws_size,
                              hipStream_t stream) {
  const float* A     = (const float*)d_in[0];  // A_ct 64x64
  const float* B     = (const float*)d_in[1];  // 1024x64
  const float* C     = (const float*)d_in[2];  // 1024x64
  const float* Dv    = (const float*)d_in[3];  // 1024
  const float* logdt = (const float*)d_in[4];  // scalar
  float* ws  = (float*)d_ws;
  float* out = (float*)d_out;                  // 1024*4096 fp32

  hipLaunchKernelGGL(k_prologue, dim3(144),  dim3(1024), 0, stream, A, B, logdt, ws);
  hipLaunchKernelGGL(k_expand,   dim3(2048), dim3(256),  0, stream, C, ws);
  hipLaunchKernelGGL(k_contract, dim3(1024), dim3(256),  0, stream, Dv, ws, out);
}